// Round 7
// baseline (3278.769 us; speedup 1.0000x reference)
//
#include <hip/hip_runtime.h>
#include <hip/hip_bf16.h>
#include <cstdint>

#define TSTEPS 512
#define BATCH  256
#define HID    512
#define INP    64
#define NGRP   16          // batch groups (16 rows each)
#define GROWS  16
#define NSL    16          // active WG slices per XCD pair-domain (32 hid cols each)
#define NWG    256
#define KTH    16          // h K-tiles (512/32)

typedef __attribute__((ext_vector_type(8))) short short8;
typedef __attribute__((ext_vector_type(4))) float f32x4;
typedef __attribute__((ext_vector_type(2))) unsigned long long ull2;

// workspace layout
#define HB0_OFF   0
#define HB1_OFF   (BATCH*HID*2)
#define HT_OFF    (2*BATCH*HID*2)
#define FLAGS_OFF (HT_OFF + BATCH*HID*4)     // [16 grp][512 t] int counters (R3 style)
#define FLAGS_SZ  (NGRP*TSTEPS*4)
#define CNT_OFF   (FLAGS_OFF + FLAGS_SZ)
#define ZERO2_SZ  (FLAGS_SZ + 64)

__device__ __forceinline__ unsigned short f2bf(float f) {
    unsigned u = __float_as_uint(f);
    return (unsigned short)((u + 0x7FFFu + ((u >> 16) & 1u)) >> 16);  // RNE
}
__device__ __forceinline__ short8 pack8(float4 a0, float4 a1) {
    short8 v;
    v[0]=(short)f2bf(a0.x); v[1]=(short)f2bf(a0.y); v[2]=(short)f2bf(a0.z); v[3]=(short)f2bf(a0.w);
    v[4]=(short)f2bf(a1.x); v[5]=(short)f2bf(a1.y); v[6]=(short)f2bf(a1.z); v[7]=(short)f2bf(a1.w);
    return v;
}
__device__ __forceinline__ float sigm(float x)  { return 1.0f/(1.0f + __expf(-x)); }
__device__ __forceinline__ float tanhf_(float x){ return 2.0f/(1.0f + __expf(-2.0f*x)) - 1.0f; }

__global__ void __launch_bounds__(256, 1)
lstm_persist(const float* __restrict__ x,   const float* __restrict__ Wih,
             const float* __restrict__ Whh, const float* __restrict__ bih,
             const float* __restrict__ bhh, const float* __restrict__ Whead,
             const float* __restrict__ bhead, float* __restrict__ out,
             char* __restrict__ ws)
{
    extern __shared__ char lds[];   // 128 KiB: forces exactly 1 WG/CU -> 32 WGs/XCD bijection
    const int tid  = threadIdx.x;
    const int lane = tid & 63;
    const int wv   = tid >> 6;
    const int l15  = lane & 15, lq = lane >> 4, l7 = lane & 7;

    unsigned short* hb0 = (unsigned short*)(ws + HB0_OFF);
    unsigned short* hb1 = (unsigned short*)(ws + HB1_OFF);
    float* hT  = (float*)(ws + HT_OFF);
    int* flags = (int*)(ws + FLAGS_OFF);
    int* cnt   = (int*)(ws + CNT_OFF);

    // ---- self-organize: first 16 claimers per XCD are the active slices ----
    int* org = (int*)(lds + 131056);
    if (tid == 0) {
        unsigned xcd;
        asm volatile("s_getreg_b32 %0, hwreg(HW_REG_XCC_ID)" : "=s"(xcd));
        xcd &= 7u;
        int slot = __hip_atomic_fetch_add(&cnt[xcd], 1, __ATOMIC_RELAXED, __HIP_MEMORY_SCOPE_AGENT);
        org[0] = slot;
        org[1] = (int)xcd;
    }
    __syncthreads();
    const int slot = org[0];
    const int xcd  = org[1];
    if (slot >= NSL) return;               // spare WGs exit (32/XCD resident, 16 active)
    const int sl = slot;
    const int gA = xcd*2, gB = xcd*2 + 1;  // this XCD's two batch groups

    const int hbase = sl*32 + wv*8;        // wave's hidden-col base
    const int gsel  = l15 >> 3;            // gate select within N-tile

    // ---- W_hh fragments resident in VGPRs: 16 Ktiles x 2 Ntiles x 4 VGPR = 128 ----
    // Ntile0 cols = [gate i: hid 0..7 | gate f: hid 0..7]; Ntile1 = [g | o]
    short8 whh[KTH][2];
    #pragma unroll
    for (int kt = 0; kt < KTH; ++kt)
        #pragma unroll
        for (int nt = 0; nt < 2; ++nt) {
            int grow = (nt*2 + gsel)*HID + hbase + l7;
            const float4* p = (const float4*)(Whh + (size_t)grow*HID + kt*32 + lq*8);
            whh[kt][nt] = pack8(p[0], p[1]);
        }
    short8 wihf[2][2];
    #pragma unroll
    for (int kt = 0; kt < 2; ++kt)
        #pragma unroll
        for (int nt = 0; nt < 2; ++nt) {
            int grow = (nt*2 + gsel)*HID + hbase + l7;
            const float4* p = (const float4*)(Wih + (size_t)grow*INP + kt*32 + lq*8);
            wihf[kt][nt] = pack8(p[0], p[1]);
        }
    float bias0, bias1;
    { int gr = (0*2 + gsel)*HID + hbase + l7; bias0 = bih[gr] + bhh[gr]; }
    { int gr = (1*2 + gsel)*HID + hbase + l7; bias1 = bih[gr] + bhh[gr]; }

    unsigned short* hgA0 = hb0 + (size_t)gA*GROWS*HID;
    unsigned short* hgA1 = hb1 + (size_t)gA*GROWS*HID;
    unsigned short* hgB0 = hb0 + (size_t)gB*GROWS*HID;
    unsigned short* hgB1 = hb1 + (size_t)gB*GROWS*HID;
    float* hTgA = hT + (size_t)gA*GROWS*HID;
    float* hTgB = hT + (size_t)gB*GROWS*HID;
    int* flA = flags + gA*TSTEPS;
    int* flB = flags + gB*TSTEPS;

    // staging map: cluster skt = tid>>4 stages (row sr, col-block skt)
    const int skt = tid >> 4, sr = tid & 15;
    char* swpA = lds + skt*1024 + sr*16;               // + s*256
    char* swpB = lds + 16384 + skt*1024 + sr*16;
    const char* srpA = lds + lane*16;                  // + kt*1024 (conflict-free)
    const char* srpB = lds + 16384 + lane*16;

    const float* xrowA = x + ((size_t)(gA*GROWS + l15)*TSTEPS)*INP + lq*8;
    const float* xrowB = x + ((size_t)(gB*GROWS + l15)*TSTEPS)*INP + lq*8;

    f32x4 cstA = {0.f, 0.f, 0.f, 0.f};
    f32x4 cstB = {0.f, 0.f, 0.f, 0.f};

    // x prefetch for t=0
    float4 xa0 = *(const float4*)(xrowA);
    float4 xa1 = *(const float4*)(xrowA + 4);
    float4 xa2 = *(const float4*)(xrowA + 32);
    float4 xa3 = *(const float4*)(xrowA + 36);
    float4 xb0 = *(const float4*)(xrowB);
    float4 xb1 = *(const float4*)(xrowB + 4);
    float4 xb2 = *(const float4*)(xrowB + 32);
    float4 xb3 = *(const float4*)(xrowB + 36);

    #pragma clang loop unroll(disable)
    for (int t = 0; t < TSTEPS; ++t) {
        // ================= phase A =================
        {
            f32x4 acc0 = {bias0, bias0, bias0, bias0};
            f32x4 acc1 = {bias1, bias1, bias1, bias1};
            {
                short8 af0 = pack8(xa0, xa1);
                short8 af1 = pack8(xa2, xa3);
                acc0 = __builtin_amdgcn_mfma_f32_16x16x32_bf16(af0, wihf[0][0], acc0, 0, 0, 0);
                acc1 = __builtin_amdgcn_mfma_f32_16x16x32_bf16(af0, wihf[0][1], acc1, 0, 0, 0);
                acc0 = __builtin_amdgcn_mfma_f32_16x16x32_bf16(af1, wihf[1][0], acc0, 0, 0, 0);
                acc1 = __builtin_amdgcn_mfma_f32_16x16x32_bf16(af1, wihf[1][1], acc1, 0, 0, 0);
            }
            if (t + 1 < TSTEPS) {   // next-x loads issue before the spin
                const float* xn = xrowA + (size_t)(t+1)*INP;
                xa0 = *(const float4*)(xn);      xa1 = *(const float4*)(xn + 4);
                xa2 = *(const float4*)(xn + 32); xa3 = *(const float4*)(xn + 36);
            }
            __builtin_amdgcn_sched_barrier(0);

            if (t) {
                const int* fl = flA + (t-1);
                while (__hip_atomic_load(fl, __ATOMIC_RELAXED, __HIP_MEMORY_SCOPE_AGENT) < NSL) {}
                asm volatile("" ::: "memory");
            }
            {
                const unsigned long long* gq = (const unsigned long long*)
                    ((const char*)((t & 1) ? hgA1 : hgA0) + sr*1024 + skt*64);
                unsigned long long hv[8];
                #pragma unroll
                for (int j = 0; j < 8; ++j)
                    hv[j] = __hip_atomic_load(gq + j, __ATOMIC_RELAXED, __HIP_MEMORY_SCOPE_AGENT);
                #pragma unroll
                for (int s = 0; s < 4; ++s) {
                    ull2 w; w[0] = hv[2*s]; w[1] = hv[2*s+1];
                    *(ull2*)(swpA + s*256) = w;
                }
            }
            __syncthreads();

            #pragma unroll
            for (int kt = 0; kt < KTH; ++kt) {
                short8 a = *(const short8*)(srpA + kt*1024);
                acc0 = __builtin_amdgcn_mfma_f32_16x16x32_bf16(a, whh[kt][0], acc0, 0, 0, 0);
                acc1 = __builtin_amdgcn_mfma_f32_16x16x32_bf16(a, whh[kt][1], acc1, 0, 0, 0);
            }

            unsigned short* hbw = (t & 1) ? hgA0 : hgA1;
            #pragma unroll
            for (int r = 0; r < 4; ++r) {
                float a0 = acc0[r], a1 = acc1[r];
                float s0 = __shfl_xor(a0, 8);
                float s1 = __shfl_xor(a1, 8);
                bool lo = (l15 < 8);
                float iv = lo ? a0 : s0;
                float fv = lo ? s0 : a0;
                float gv = lo ? a1 : s1;
                float ov = lo ? s1 : a1;
                float c  = sigm(fv)*cstA[r] + sigm(iv)*tanhf_(gv);
                cstA[r] = c;
                float h  = sigm(ov)*tanhf_(c);
                if (lo) {
                    int idx = (lq*4 + r)*HID + hbase + l7;
                    hbw[idx] = f2bf(h);
                    if (t == TSTEPS-1) hTgA[idx] = h;
                }
            }
            __syncthreads();   // all waves' h stores drained -> publish
            if (tid == 0)
                __hip_atomic_fetch_add(&flA[t], 1, __ATOMIC_RELAXED, __HIP_MEMORY_SCOPE_AGENT);
        }
        // ================= phase B =================
        {
            f32x4 acc0 = {bias0, bias0, bias0, bias0};
            f32x4 acc1 = {bias1, bias1, bias1, bias1};
            {
                short8 af0 = pack8(xb0, xb1);
                short8 af1 = pack8(xb2, xb3);
                acc0 = __builtin_amdgcn_mfma_f32_16x16x32_bf16(af0, wihf[0][0], acc0, 0, 0, 0);
                acc1 = __builtin_amdgcn_mfma_f32_16x16x32_bf16(af0, wihf[0][1], acc1, 0, 0, 0);
                acc0 = __builtin_amdgcn_mfma_f32_16x16x32_bf16(af1, wihf[1][0], acc0, 0, 0, 0);
                acc1 = __builtin_amdgcn_mfma_f32_16x16x32_bf16(af1, wihf[1][1], acc1, 0, 0, 0);
            }
            if (t + 1 < TSTEPS) {
                const float* xn = xrowB + (size_t)(t+1)*INP;
                xb0 = *(const float4*)(xn);      xb1 = *(const float4*)(xn + 4);
                xb2 = *(const float4*)(xn + 32); xb3 = *(const float4*)(xn + 36);
            }
            __builtin_amdgcn_sched_barrier(0);

            if (t) {
                const int* fl = flB + (t-1);
                while (__hip_atomic_load(fl, __ATOMIC_RELAXED, __HIP_MEMORY_SCOPE_AGENT) < NSL) {}
                asm volatile("" ::: "memory");
            }
            {
                const unsigned long long* gq = (const unsigned long long*)
                    ((const char*)((t & 1) ? hgB1 : hgB0) + sr*1024 + skt*64);
                unsigned long long hv[8];
                #pragma unroll
                for (int j = 0; j < 8; ++j)
                    hv[j] = __hip_atomic_load(gq + j, __ATOMIC_RELAXED, __HIP_MEMORY_SCOPE_AGENT);
                #pragma unroll
                for (int s = 0; s < 4; ++s) {
                    ull2 w; w[0] = hv[2*s]; w[1] = hv[2*s+1];
                    *(ull2*)(swpB + s*256) = w;
                }
            }
            __syncthreads();

            #pragma unroll
            for (int kt = 0; kt < KTH; ++kt) {
                short8 a = *(const short8*)(srpB + kt*1024);
                acc0 = __builtin_amdgcn_mfma_f32_16x16x32_bf16(a, whh[kt][0], acc0, 0, 0, 0);
                acc1 = __builtin_amdgcn_mfma_f32_16x16x32_bf16(a, whh[kt][1], acc1, 0, 0, 0);
            }

            unsigned short* hbw = (t & 1) ? hgB0 : hgB1;
            #pragma unroll
            for (int r = 0; r < 4; ++r) {
                float a0 = acc0[r], a1 = acc1[r];
                float s0 = __shfl_xor(a0, 8);
                float s1 = __shfl_xor(a1, 8);
                bool lo = (l15 < 8);
                float iv = lo ? a0 : s0;
                float fv = lo ? s0 : a0;
                float gv = lo ? a1 : s1;
                float ov = lo ? s1 : a1;
                float c  = sigm(fv)*cstB[r] + sigm(iv)*tanhf_(gv);
                cstB[r] = c;
                float h  = sigm(ov)*tanhf_(c);
                if (lo) {
                    int idx = (lq*4 + r)*HID + hbase + l7;
                    hbw[idx] = f2bf(h);
                    if (t == TSTEPS-1) hTgB[idx] = h;
                }
            }
            __syncthreads();
            if (tid == 0)
                __hip_atomic_fetch_add(&flB[t], 1, __ATOMIC_RELAXED, __HIP_MEMORY_SCOPE_AGENT);
        }
    }

    // ---- heads: slice-0 WG of each XCD does both groups ----
    if (sl == 0) {
        #pragma clang loop unroll(disable)
        for (int pp = 0; pp < 2; ++pp) {
            const int gg = pp ? gB : gA;
            const float* hTg = hT + (size_t)gg*GROWS*HID;
            const int* fl = flags + gg*TSTEPS + (TSTEPS-1);
            while (__hip_atomic_load(fl, __ATOMIC_RELAXED, __HIP_MEMORY_SCOPE_AGENT) < NSL) {}
            asm volatile("" ::: "memory");
            __syncthreads();
            {
                const float4* gp = (const float4*)((const char*)hTg + tid*128);
                float4* wp = (float4*)(lds + tid*128);
                #pragma unroll
                for (int j = 0; j < 8; ++j) wp[j] = gp[j];
            }
            __syncthreads();
            const float* hsm = (const float*)lds;
            for (int idx = tid; idx < 6*GROWS*3; idx += 256) {
                int k = idx / (GROWS*3), rem = idx % (GROWS*3);
                int row = rem / 3, o = rem % 3;
                const float* wp = Whead + ((size_t)k*3 + o)*HID;
                const float* hp = hsm + row*HID;
                float s = 0.f;
                for (int hh = 0; hh < HID; hh += 4) {
                    float4 hv = *(const float4*)(hp + hh);
                    float4 wv = *(const float4*)(wp + hh);
                    s += hv.x*wv.x + hv.y*wv.y + hv.z*wv.z + hv.w*wv.w;
                }
                out[((size_t)k*BATCH + gg*GROWS + row)*3 + o] = s + bhead[k*3 + o];
            }
            __syncthreads();
        }
    }
}

extern "C" void kernel_launch(void* const* d_in, const int* in_sizes, int n_in,
                              void* d_out, int out_size, void* d_ws, size_t ws_size,
                              hipStream_t stream) {
    (void)in_sizes; (void)n_in; (void)out_size; (void)ws_size;
    const float* x     = (const float*)d_in[0];
    const float* Wih   = (const float*)d_in[1];
    const float* Whh   = (const float*)d_in[2];
    const float* bih   = (const float*)d_in[3];
    const float* bhh   = (const float*)d_in[4];
    const float* Whead = (const float*)d_in[5];
    const float* bhead = (const float*)d_in[6];
    char* ws = (char*)d_ws;

    (void)hipFuncSetAttribute((const void*)lstm_persist,
                              hipFuncAttributeMaxDynamicSharedMemorySize, 131072);

    // per-launch reset: h_0 = 0, flags = 0, xcd slot counters = 0
    (void)hipMemsetAsync(ws + HB0_OFF, 0, BATCH*HID*2, stream);
    (void)hipMemsetAsync(ws + FLAGS_OFF, 0, ZERO2_SZ, stream);

    hipLaunchKernelGGL(lstm_persist, dim3(NWG), dim3(256), 131072, stream,
                       x, Wih, Whh, bih, bhh, Whead, bhead, (float*)d_out, ws);
}

// Round 8
// 2007.248 us; speedup vs baseline: 1.6335x; 1.6335x over previous
//
#include <hip/hip_runtime.h>
#include <hip/hip_bf16.h>
#include <cstdint>

#define TSTEPS 512
#define BATCH  256
#define HID    512
#define INP    64
#define NGRP   16          // batch groups (16 rows each)
#define GROWS  16
#define NSL    16          // WG slices per group (32 hid cols each)
#define NWG    256
#define KTH    16          // h K-tiles (512/32)

typedef __attribute__((ext_vector_type(8))) short short8;
typedef __attribute__((ext_vector_type(4))) float f32x4;
typedef __attribute__((ext_vector_type(2))) float f32x2;

// workspace layout
#define HB0_OFF   0
#define HB1_OFF   (BATCH*HID*2)
#define HT_OFF    (2*BATCH*HID*2)
#define FLAGS_OFF (HT_OFF + BATCH*HID*4)     // [16 grp][512 t] int counters (R3 style)
#define FLAGS_SZ  (NGRP*TSTEPS*4)
#define CNT_OFF   (FLAGS_OFF + FLAGS_SZ)
#define ZERO2_SZ  (FLAGS_SZ + 64)

__device__ __forceinline__ unsigned cvtpk(float a, float b) {
    unsigned r;
    asm("v_cvt_pk_bf16_f32 %0, %1, %2" : "=v"(r) : "v"(a), "v"(b));
    return r;   // low16 = bf16(a), high16 = bf16(b), RNE
}
__device__ __forceinline__ short8 pack8(float4 a0, float4 a1) {
    uint4 u = { cvtpk(a0.x, a0.y), cvtpk(a0.z, a0.w),
                cvtpk(a1.x, a1.y), cvtpk(a1.z, a1.w) };
    return __builtin_bit_cast(short8, u);
}
__device__ __forceinline__ float sigm(float x)  { return 1.0f/(1.0f + __expf(-x)); }
__device__ __forceinline__ float tanhf_(float x){ return 2.0f/(1.0f + __expf(-2.0f*x)) - 1.0f; }

__global__ void __launch_bounds__(256, 1)
lstm_persist(const float* __restrict__ x,   const float* __restrict__ Wih,
             const float* __restrict__ Whh, const float* __restrict__ bih,
             const float* __restrict__ bhh, const float* __restrict__ Whead,
             const float* __restrict__ bhead, float* __restrict__ out,
             char* __restrict__ ws)
{
    extern __shared__ char lds[];   // 128 KiB requested (forces 1 WG/CU); 16 KiB stage
    const int tid  = threadIdx.x;
    const int lane = tid & 63;
    const int wv   = tid >> 6;
    const int l15  = lane & 15, lq = lane >> 4, l7 = lane & 7;

    unsigned short* hb0 = (unsigned short*)(ws + HB0_OFF);
    unsigned short* hb1 = (unsigned short*)(ws + HB1_OFF);
    float* hT  = (float*)(ws + HT_OFF);
    int* flags = (int*)(ws + FLAGS_OFF);
    int* cnt   = (int*)(ws + CNT_OFF);

    // ---- self-organize by XCD: 32 WGs/XCD (capacity-guaranteed) -> 2 groups x 16 slices ----
    int* org = (int*)(lds + 131056);
    if (tid == 0) {
        unsigned xcd;
        asm volatile("s_getreg_b32 %0, hwreg(HW_REG_XCC_ID)" : "=s"(xcd));
        xcd &= 7u;
        int slot = __hip_atomic_fetch_add(&cnt[xcd], 1, __ATOMIC_RELAXED, __HIP_MEMORY_SCOPE_AGENT) & 31;
        org[0] = (int)xcd * 2 + (slot >> 4);
        org[1] = slot & 15;
    }
    __syncthreads();
    const int g  = org[0];
    const int sl = org[1];
    const int hbase = sl*32 + wv*8;        // wave's hidden-col base
    const int gsel  = l15 >> 3;            // gate select within N-tile

    // ---- W_hh fragments resident in VGPRs: 16 Ktiles x 2 Ntiles x 4 VGPR = 128 ----
    // Ntile0 cols = [gate i: hid 0..7 | gate f: hid 0..7]; Ntile1 = [g | o]
    short8 whh[KTH][2];
    #pragma unroll
    for (int kt = 0; kt < KTH; ++kt)
        #pragma unroll
        for (int nt = 0; nt < 2; ++nt) {
            int grow = (nt*2 + gsel)*HID + hbase + l7;
            const float4* p = (const float4*)(Whh + (size_t)grow*HID + kt*32 + lq*8);
            whh[kt][nt] = pack8(p[0], p[1]);
        }
    short8 wihf[2][2];
    #pragma unroll
    for (int kt = 0; kt < 2; ++kt)
        #pragma unroll
        for (int nt = 0; nt < 2; ++nt) {
            int grow = (nt*2 + gsel)*HID + hbase + l7;
            const float4* p = (const float4*)(Wih + (size_t)grow*INP + kt*32 + lq*8);
            wihf[kt][nt] = pack8(p[0], p[1]);
        }
    float bias0, bias1;
    { int gr = (0*2 + gsel)*HID + hbase + l7; bias0 = bih[gr] + bhh[gr]; }
    { int gr = (1*2 + gsel)*HID + hbase + l7; bias1 = bih[gr] + bhh[gr]; }

    unsigned short* hg0 = hb0 + (size_t)g*GROWS*HID;
    unsigned short* hg1 = hb1 + (size_t)g*GROWS*HID;
    float*          hTg = hT  + (size_t)g*GROWS*HID;
    int* flg = flags + g*TSTEPS;

    // ---- staging offsets (coalesced global -> swizzled LDS fragment layout) ----
    // thread t, j: global byte B = j*2048 + t*8 (contiguous 512B per wave instr).
    // LDS fragment layout per kt block (1KB): [s(=cw>>3)][row^kt&7][8 elems]
    int wo[8];
    #pragma unroll
    for (int j = 0; j < 8; ++j) {
        int B = j*2048 + tid*8;
        int row = B >> 10, col = (B & 1023) >> 1;
        int kt = col >> 5, cw = col & 31, s = cw >> 3, e = cw & 7;
        wo[j] = kt*1024 + s*256 + ((row ^ (kt & 7)) << 4) + e*2;
    }
    int ro[KTH];
    #pragma unroll
    for (int kt = 0; kt < KTH; ++kt)
        ro[kt] = kt*1024 + lq*256 + ((l15 ^ (kt & 7)) << 4);

    const float* xrow = x + ((size_t)(g*GROWS + l15)*TSTEPS)*INP + lq*8;

    f32x2 cst = {0.f, 0.f};
    const bool lo = (l15 < 8);

    // x prefetch for t=0
    float4 xv0 = *(const float4*)(xrow);
    float4 xv1 = *(const float4*)(xrow + 4);
    float4 xv2 = *(const float4*)(xrow + 32);
    float4 xv3 = *(const float4*)(xrow + 36);

    #pragma clang loop unroll(disable)
    for (int t = 0; t < TSTEPS; ++t) {
        if (t) {
            const int* fl = flg + (t-1);
            while (__hip_atomic_load(fl, __ATOMIC_RELAXED, __HIP_MEMORY_SCOPE_AGENT) < NSL) {}
            asm volatile("" ::: "memory");
        }

        // issue stage loads FIRST (coalesced: 512B contiguous per wave per instr)
        const unsigned long long* gq = (const unsigned long long*)((t & 1) ? hg1 : hg0);
        unsigned long long hv[8];
        #pragma unroll
        for (int j = 0; j < 8; ++j)
            hv[j] = __hip_atomic_load(gq + j*256 + tid, __ATOMIC_RELAXED, __HIP_MEMORY_SCOPE_AGENT);
        __builtin_amdgcn_sched_barrier(0);

        // x-projection MFMAs overlap the stage-load latency; 4 independent chains
        f32x4 a0 = {bias0, bias0, bias0, bias0};
        f32x4 a1 = {bias1, bias1, bias1, bias1};
        f32x4 b0 = {0.f, 0.f, 0.f, 0.f};
        f32x4 b1 = {0.f, 0.f, 0.f, 0.f};
        {
            short8 af0 = pack8(xv0, xv1);
            short8 af1 = pack8(xv2, xv3);
            a0 = __builtin_amdgcn_mfma_f32_16x16x32_bf16(af0, wihf[0][0], a0, 0, 0, 0);
            a1 = __builtin_amdgcn_mfma_f32_16x16x32_bf16(af0, wihf[0][1], a1, 0, 0, 0);
            b0 = __builtin_amdgcn_mfma_f32_16x16x32_bf16(af1, wihf[1][0], b0, 0, 0, 0);
            b1 = __builtin_amdgcn_mfma_f32_16x16x32_bf16(af1, wihf[1][1], b1, 0, 0, 0);
        }
        if (t + 1 < TSTEPS) {   // next-x loads: in flight during MFMA+epilogue
            const float* xn = xrow + (size_t)(t+1)*INP;
            xv0 = *(const float4*)(xn);      xv1 = *(const float4*)(xn + 4);
            xv2 = *(const float4*)(xn + 32); xv3 = *(const float4*)(xn + 36);
        }

        // scatter staged data into LDS fragment layout (waits on hv via vmcnt)
        #pragma unroll
        for (int j = 0; j < 8; ++j)
            *(unsigned long long*)(lds + wo[j]) = hv[j];
        __syncthreads();

        // h-part MFMAs: even kt -> a-chains, odd kt -> b-chains
        #pragma unroll
        for (int k2 = 0; k2 < 8; ++k2) {
            short8 ae = *(const short8*)(lds + ro[2*k2]);
            short8 aoo = *(const short8*)(lds + ro[2*k2+1]);
            a0 = __builtin_amdgcn_mfma_f32_16x16x32_bf16(ae,  whh[2*k2][0],   a0, 0, 0, 0);
            a1 = __builtin_amdgcn_mfma_f32_16x16x32_bf16(ae,  whh[2*k2][1],   a1, 0, 0, 0);
            b0 = __builtin_amdgcn_mfma_f32_16x16x32_bf16(aoo, whh[2*k2+1][0], b0, 0, 0, 0);
            b1 = __builtin_amdgcn_mfma_f32_16x16x32_bf16(aoo, whh[2*k2+1][1], b1, 0, 0, 0);
        }
        f32x4 acc0 = a0 + b0;
        f32x4 acc1 = a1 + b1;

        // lane-split epilogue: lo lanes rows r={0,1}, hi lanes rows r={2,3}
        // C layout col=lane&15, row=(lane>>4)*4+r
        float s0[4], s1[4];
        #pragma unroll
        for (int r = 0; r < 4; ++r) {
            s0[r] = __shfl_xor(acc0[r], 8);
            s1[r] = __shfl_xor(acc1[r], 8);
        }
        unsigned short* hbw = (t & 1) ? hg0 : hg1;
        #pragma unroll
        for (int rr = 0; rr < 2; ++rr) {
            float iv = lo ? acc0[rr] : s0[rr+2];
            float fv = lo ? s0[rr]   : acc0[rr+2];
            float gv = lo ? acc1[rr] : s1[rr+2];
            float ov = lo ? s1[rr]   : acc1[rr+2];
            float c  = sigm(fv)*cst[rr] + sigm(iv)*tanhf_(gv);
            cst[rr] = c;
            float h  = sigm(ov)*tanhf_(c);
            int row  = lq*4 + rr + (lo ? 0 : 2);
            int idx  = row*HID + hbase + l7;
            hbw[idx] = (unsigned short)(cvtpk(h, h) & 0xffffu);
            if (t == TSTEPS-1) hTg[idx] = h;
        }
        __syncthreads();   // drains stores (implicit vmcnt(0)) -> publish
        if (tid == 0)
            __hip_atomic_fetch_add(&flg[t], 1, __ATOMIC_RELAXED, __HIP_MEMORY_SCOPE_AGENT);
    }

    // ---- heads: slice-0 WG of each group ----
    if (sl == 0) {
        const int* fl = flg + (TSTEPS-1);
        while (__hip_atomic_load(fl, __ATOMIC_RELAXED, __HIP_MEMORY_SCOPE_AGENT) < NSL) {}
        asm volatile("" ::: "memory");
        __syncthreads();
        // stage hT tile (16x512 f32 = 32 KiB) into LDS; never loaded before by this WG
        {
            const float4* gp = (const float4*)((const char*)hTg + tid*128);
            float4* wp = (float4*)(lds + tid*128);
            #pragma unroll
            for (int j = 0; j < 8; ++j) wp[j] = gp[j];
        }
        __syncthreads();
        const float* hsm = (const float*)lds;
        for (int idx = tid; idx < 6*GROWS*3; idx += 256) {
            int k = idx / (GROWS*3), rem = idx % (GROWS*3);
            int row = rem / 3, o = rem % 3;
            const float* wp = Whead + ((size_t)k*3 + o)*HID;
            const float* hp = hsm + row*HID;
            float s = 0.f;
            for (int hh = 0; hh < HID; hh += 4) {
                float4 hv = *(const float4*)(hp + hh);
                float4 wv = *(const float4*)(wp + hh);
                s += hv.x*wv.x + hv.y*wv.y + hv.z*wv.z + hv.w*wv.w;
            }
            out[((size_t)k*BATCH + g*GROWS + row)*3 + o] = s + bhead[k*3 + o];
        }
    }
}

extern "C" void kernel_launch(void* const* d_in, const int* in_sizes, int n_in,
                              void* d_out, int out_size, void* d_ws, size_t ws_size,
                              hipStream_t stream) {
    (void)in_sizes; (void)n_in; (void)out_size; (void)ws_size;
    const float* x     = (const float*)d_in[0];
    const float* Wih   = (const float*)d_in[1];
    const float* Whh   = (const float*)d_in[2];
    const float* bih   = (const float*)d_in[3];
    const float* bhh   = (const float*)d_in[4];
    const float* Whead = (const float*)d_in[5];
    const float* bhead = (const float*)d_in[6];
    char* ws = (char*)d_ws;

    (void)hipFuncSetAttribute((const void*)lstm_persist,
                              hipFuncAttributeMaxDynamicSharedMemorySize, 131072);

    // per-launch reset: h_0 = 0, flags = 0, xcd slot counters = 0
    (void)hipMemsetAsync(ws + HB0_OFF, 0, BATCH*HID*2, stream);
    (void)hipMemsetAsync(ws + FLAGS_OFF, 0, ZERO2_SZ, stream);

    hipLaunchKernelGGL(lstm_persist, dim3(NWG), dim3(256), 131072, stream,
                       x, Wih, Whh, bih, bhh, Whead, bhead, (float*)d_out, ws);
}

// Round 9
// 1266.386 us; speedup vs baseline: 2.5891x; 1.5850x over previous
//
#include <hip/hip_runtime.h>
#include <hip/hip_bf16.h>
#include <cstdint>

#define TSTEPS 512
#define BATCH  256
#define HID    512
#define INP    64
#define NGRP   16          // batch groups (16 rows each)
#define GROWS  16
#define NSL    16          // WG slices per group (32 hid cols each)
#define NWG    256
#define KTH    16          // h K-tiles (512/32)
#define RING   8           // h ring depth: reuse distance ~140KB >> 32KB L1

typedef __attribute__((ext_vector_type(8))) short short8;
typedef __attribute__((ext_vector_type(4))) float f32x4;
typedef __attribute__((ext_vector_type(2))) float f32x2;
typedef __attribute__((ext_vector_type(2))) unsigned long long ull2;

// workspace layout
#define HB_OFF    0                            // RING x (BATCH*HID*2) h slots
#define HT_OFF    (RING*BATCH*HID*2)
#define FLAGS_OFF (HT_OFF + BATCH*HID*4)       // [16 grp][512 t] int counters
#define FLAGS_SZ  (NGRP*TSTEPS*4)
#define CNT_OFF   (FLAGS_OFF + FLAGS_SZ)
#define ZERO2_SZ  (FLAGS_SZ + 64)

__device__ __forceinline__ unsigned cvtpk(float a, float b) {
    unsigned r;
    asm("v_cvt_pk_bf16_f32 %0, %1, %2" : "=v"(r) : "v"(a), "v"(b));
    return r;   // low16 = bf16(a), high16 = bf16(b), RNE
}
__device__ __forceinline__ short8 pack8(float4 a0, float4 a1) {
    uint4 u = { cvtpk(a0.x, a0.y), cvtpk(a0.z, a0.w),
                cvtpk(a1.x, a1.y), cvtpk(a1.z, a1.w) };
    return __builtin_bit_cast(short8, u);
}
__device__ __forceinline__ float sigm(float x)  { return 1.0f/(1.0f + __expf(-x)); }
__device__ __forceinline__ float tanhf_(float x){ return 2.0f/(1.0f + __expf(-2.0f*x)) - 1.0f; }

__global__ void __launch_bounds__(256, 1)
lstm_persist(const float* __restrict__ x,   const float* __restrict__ Wih,
             const float* __restrict__ Whh, const float* __restrict__ bih,
             const float* __restrict__ bhh, const float* __restrict__ Whead,
             const float* __restrict__ bhead, float* __restrict__ out,
             char* __restrict__ ws)
{
    extern __shared__ char lds[];   // 128 KiB requested (forces 1 WG/CU); 16 KiB stage
    const int tid  = threadIdx.x;
    const int lane = tid & 63;
    const int wv   = tid >> 6;
    const int l15  = lane & 15, lq = lane >> 4, l7 = lane & 7;

    unsigned short* hb = (unsigned short*)(ws + HB_OFF);
    float* hT  = (float*)(ws + HT_OFF);
    int* flags = (int*)(ws + FLAGS_OFF);
    int* cnt   = (int*)(ws + CNT_OFF);

    // ---- self-organize by XCD: 32 WGs/XCD (capacity-guaranteed) -> 2 groups x 16 slices ----
    int* org = (int*)(lds + 131056);
    if (tid == 0) {
        unsigned xcd;
        asm volatile("s_getreg_b32 %0, hwreg(HW_REG_XCC_ID)" : "=s"(xcd));
        xcd &= 7u;
        int slot = __hip_atomic_fetch_add(&cnt[xcd], 1, __ATOMIC_RELAXED, __HIP_MEMORY_SCOPE_AGENT) & 31;
        org[0] = (int)xcd * 2 + (slot >> 4);
        org[1] = slot & 15;
    }
    __syncthreads();
    const int g  = org[0];
    const int sl = org[1];
    const int hbase = sl*32 + wv*8;        // wave's hidden-col base
    const int gsel  = l15 >> 3;            // gate select within N-tile

    // ---- W_hh fragments resident in VGPRs: 16 Ktiles x 2 Ntiles x 4 VGPR = 128 ----
    // Ntile0 cols = [gate i: hid 0..7 | gate f: hid 0..7]; Ntile1 = [g | o]
    short8 whh[KTH][2];
    #pragma unroll
    for (int kt = 0; kt < KTH; ++kt)
        #pragma unroll
        for (int nt = 0; nt < 2; ++nt) {
            int grow = (nt*2 + gsel)*HID + hbase + l7;
            const float4* p = (const float4*)(Whh + (size_t)grow*HID + kt*32 + lq*8);
            whh[kt][nt] = pack8(p[0], p[1]);
        }
    short8 wihf[2][2];
    #pragma unroll
    for (int kt = 0; kt < 2; ++kt)
        #pragma unroll
        for (int nt = 0; nt < 2; ++nt) {
            int grow = (nt*2 + gsel)*HID + hbase + l7;
            const float4* p = (const float4*)(Wih + (size_t)grow*INP + kt*32 + lq*8);
            wihf[kt][nt] = pack8(p[0], p[1]);
        }
    float bias0, bias1;
    { int gr = (0*2 + gsel)*HID + hbase + l7; bias0 = bih[gr] + bhh[gr]; }
    { int gr = (1*2 + gsel)*HID + hbase + l7; bias1 = bih[gr] + bhh[gr]; }

    unsigned short* hgrp = hb + (size_t)g*GROWS*HID;   // + slot*(BATCH*HID)
    float*          hTg  = hT + (size_t)g*GROWS*HID;
    int* flg = flags + g*TSTEPS;

    // staging map (R3's measured-conflict-free one): cluster skt stages (row sr, col-block skt)
    const int skt = tid >> 4, sr = tid & 15;
    char* swp = lds + skt*1024 + sr*16;            // + s*256 for k-sub-block s=0..3
    const char* srp = lds + lane*16;               // frag read: + kt*1024

    const float* xrow = x + ((size_t)(g*GROWS + l15)*TSTEPS)*INP + lq*8;

    f32x2 cst = {0.f, 0.f};
    const bool lo = (l15 < 8);

    // x prefetch for t=0
    float4 xv0 = *(const float4*)(xrow);
    float4 xv1 = *(const float4*)(xrow + 4);
    float4 xv2 = *(const float4*)(xrow + 32);
    float4 xv3 = *(const float4*)(xrow + 36);

    #pragma clang loop unroll(disable)
    for (int t = 0; t < TSTEPS; ++t) {
        // 4 independent accumulator chains: x kt0 -> a*, x kt1 -> b*
        f32x4 a0 = {bias0, bias0, bias0, bias0};
        f32x4 a1 = {bias1, bias1, bias1, bias1};
        f32x4 b0 = {0.f, 0.f, 0.f, 0.f};
        f32x4 b1 = {0.f, 0.f, 0.f, 0.f};
        {
            short8 af0 = pack8(xv0, xv1);
            short8 af1 = pack8(xv2, xv3);
            a0 = __builtin_amdgcn_mfma_f32_16x16x32_bf16(af0, wihf[0][0], a0, 0, 0, 0);
            a1 = __builtin_amdgcn_mfma_f32_16x16x32_bf16(af0, wihf[0][1], a1, 0, 0, 0);
            b0 = __builtin_amdgcn_mfma_f32_16x16x32_bf16(af1, wihf[1][0], b0, 0, 0, 0);
            b1 = __builtin_amdgcn_mfma_f32_16x16x32_bf16(af1, wihf[1][1], b1, 0, 0, 0);
        }
        // x loads for t+1: issue BEFORE the spin -> HBM latency hides under the wait
        if (t + 1 < TSTEPS) {
            const float* xn = xrow + (size_t)(t+1)*INP;
            xv0 = *(const float4*)(xn);      xv1 = *(const float4*)(xn + 4);
            xv2 = *(const float4*)(xn + 32); xv3 = *(const float4*)(xn + 36);
        }
        __builtin_amdgcn_sched_barrier(0);

        if (t) {
            const int* fl = flg + (t-1);
            while (__hip_atomic_load(fl, __ATOMIC_RELAXED, __HIP_MEMORY_SCOPE_AGENT) < NSL) {}
            asm volatile("" ::: "memory");   // compiler fence: no hoisting stage loads above poll
        }

        // stage h_{t-1} (slot t&7) into LDS, A-fragment order, via PLAIN cached loads:
        // each thread reads its own 64B line (4x16B, 1 L2 fill + 3 L1 hits).
        // Freshness: ring-8 => this slot's lines were evicted ~140KB ago; producer
        // self-stored lines hold its own correct h values.
        {
            const char* gsrc = (const char*)(hgrp + (size_t)(t & (RING-1))*BATCH*HID)
                               + sr*1024 + skt*64;
            ull2 w0 = *(const ull2*)(gsrc);
            ull2 w1 = *(const ull2*)(gsrc + 16);
            ull2 w2 = *(const ull2*)(gsrc + 32);
            ull2 w3 = *(const ull2*)(gsrc + 48);
            *(ull2*)(swp      ) = w0;
            *(ull2*)(swp + 256) = w1;
            *(ull2*)(swp + 512) = w2;
            *(ull2*)(swp + 768) = w3;
        }
        __syncthreads();

        // h-part MFMAs: even kt -> a-chains, odd kt -> b-chains (halved dep depth)
        #pragma unroll
        for (int k2 = 0; k2 < 8; ++k2) {
            short8 ae = *(const short8*)(srp + (2*k2  )*1024);
            short8 ao = *(const short8*)(srp + (2*k2+1)*1024);
            a0 = __builtin_amdgcn_mfma_f32_16x16x32_bf16(ae, whh[2*k2  ][0], a0, 0, 0, 0);
            a1 = __builtin_amdgcn_mfma_f32_16x16x32_bf16(ae, whh[2*k2  ][1], a1, 0, 0, 0);
            b0 = __builtin_amdgcn_mfma_f32_16x16x32_bf16(ao, whh[2*k2+1][0], b0, 0, 0, 0);
            b1 = __builtin_amdgcn_mfma_f32_16x16x32_bf16(ao, whh[2*k2+1][1], b1, 0, 0, 0);
        }
        f32x4 acc0 = a0 + b0;
        f32x4 acc1 = a1 + b1;

        // lane-split epilogue: lo lanes rows {0,1}, hi lanes rows {2,3} (half the transcendentals)
        // C layout col=lane&15, row=(lane>>4)*4+r; cols 0..7 = gates i/g, 8..15 = f/o
        float s0[4], s1[4];
        #pragma unroll
        for (int r = 0; r < 4; ++r) {
            s0[r] = __shfl_xor(acc0[r], 8);
            s1[r] = __shfl_xor(acc1[r], 8);
        }
        unsigned short* hbw = hgrp + (size_t)((t+1) & (RING-1))*BATCH*HID;
        #pragma unroll
        for (int rr = 0; rr < 2; ++rr) {
            float iv = lo ? acc0[rr] : s0[rr+2];
            float fv = lo ? s0[rr]   : acc0[rr+2];
            float gv = lo ? acc1[rr] : s1[rr+2];
            float ov = lo ? s1[rr]   : acc1[rr+2];
            float c  = sigm(fv)*cst[rr] + sigm(iv)*tanhf_(gv);
            cst[rr] = c;
            float h  = sigm(ov)*tanhf_(c);
            int row  = lq*4 + rr + (lo ? 0 : 2);
            int idx  = row*HID + hbase + l7;
            hbw[idx] = (unsigned short)(cvtpk(h, h) & 0xffffu);
            if (t == TSTEPS-1) hTg[idx] = h;
        }
        __syncthreads();   // implicit vmcnt(0): all 4 waves' h stores in L2 -> publish
        if (tid == 0)
            __hip_atomic_fetch_add(&flg[t], 1, __ATOMIC_RELAXED, __HIP_MEMORY_SCOPE_AGENT);
    }

    // ---- heads: slice-0 WG of each group ----
    if (sl == 0) {
        const int* fl = flg + (TSTEPS-1);
        while (__hip_atomic_load(fl, __ATOMIC_RELAXED, __HIP_MEMORY_SCOPE_AGENT) < NSL) {}
        asm volatile("" ::: "memory");
        __syncthreads();
        // stage hT tile (16x512 f32 = 32 KiB) into LDS; these addresses were never
        // read before by this WG -> no stale-L1 path, plain loads safe.
        {
            const float4* gp = (const float4*)((const char*)hTg + tid*128);
            float4* wp = (float4*)(lds + tid*128);
            #pragma unroll
            for (int j = 0; j < 8; ++j) wp[j] = gp[j];
        }
        __syncthreads();
        const float* hsm = (const float*)lds;
        for (int idx = tid; idx < 6*GROWS*3; idx += 256) {
            int k = idx / (GROWS*3), rem = idx % (GROWS*3);
            int row = rem / 3, o = rem % 3;
            const float* wp = Whead + ((size_t)k*3 + o)*HID;
            const float* hp = hsm + row*HID;
            float s = 0.f;
            for (int hh = 0; hh < HID; hh += 4) {
                float4 hv = *(const float4*)(hp + hh);
                float4 wv = *(const float4*)(wp + hh);
                s += hv.x*wv.x + hv.y*wv.y + hv.z*wv.z + hv.w*wv.w;
            }
            out[((size_t)k*BATCH + g*GROWS + row)*3 + o] = s + bhead[k*3 + o];
        }
    }
}

extern "C" void kernel_launch(void* const* d_in, const int* in_sizes, int n_in,
                              void* d_out, int out_size, void* d_ws, size_t ws_size,
                              hipStream_t stream) {
    (void)in_sizes; (void)n_in; (void)out_size; (void)ws_size;
    const float* x     = (const float*)d_in[0];
    const float* Wih   = (const float*)d_in[1];
    const float* Whh   = (const float*)d_in[2];
    const float* bih   = (const float*)d_in[3];
    const float* bhh   = (const float*)d_in[4];
    const float* Whead = (const float*)d_in[5];
    const float* bhead = (const float*)d_in[6];
    char* ws = (char*)d_ws;

    (void)hipFuncSetAttribute((const void*)lstm_persist,
                              hipFuncAttributeMaxDynamicSharedMemorySize, 131072);

    // per-launch reset: h_0 slot 0 = 0, flags = 0, xcd slot counters = 0
    (void)hipMemsetAsync(ws + HB_OFF, 0, BATCH*HID*2, stream);
    (void)hipMemsetAsync(ws + FLAGS_OFF, 0, ZERO2_SZ, stream);

    hipLaunchKernelGGL(lstm_persist, dim3(NWG), dim3(256), 131072, stream,
                       x, Wih, Whh, bih, bhh, Whead, bhead, (float*)d_out, ws);
}

// Round 10
// 1106.802 us; speedup vs baseline: 2.9624x; 1.1442x over previous
//
#include <hip/hip_runtime.h>
#include <hip/hip_bf16.h>
#include <cstdint>

#define TSTEPS 512
#define BATCH  256
#define HID    512
#define INP    64
#define NGRP   16          // batch groups (16 rows each)
#define GROWS  16
#define NSL    16          // WG slices per group (32 hid cols each)
#define NWG    256
#define KTH    16          // h K-tiles (512/32)
#define RING   8           // h ring depth: reuse distance ~140KB >> 32KB L1

typedef __attribute__((ext_vector_type(8))) short short8;
typedef __attribute__((ext_vector_type(4))) float f32x4;
typedef __attribute__((ext_vector_type(2))) float f32x2;
typedef __attribute__((ext_vector_type(2))) unsigned long long ull2;

// workspace layout
#define HB_OFF    0                            // RING x (BATCH*HID*2) h slots
#define HT_OFF    (RING*BATCH*HID*2)
#define FLAGS_OFF (HT_OFF + BATCH*HID*4)       // [16 grp][512 t] int counters
#define FLAGS_SZ  (NGRP*TSTEPS*4)
#define CNT_OFF   (FLAGS_OFF + FLAGS_SZ)
#define ZERO2_SZ  (FLAGS_SZ + 64)

__device__ __forceinline__ unsigned cvtpk(float a, float b) {
    unsigned r;
    asm("v_cvt_pk_bf16_f32 %0, %1, %2" : "=v"(r) : "v"(a), "v"(b));
    return r;   // low16 = bf16(a), high16 = bf16(b), RNE
}
__device__ __forceinline__ short8 pack8(float4 a0, float4 a1) {
    uint4 u = { cvtpk(a0.x, a0.y), cvtpk(a0.z, a0.w),
                cvtpk(a1.x, a1.y), cvtpk(a1.z, a1.w) };
    return __builtin_bit_cast(short8, u);
}
__device__ __forceinline__ float sigm(float x)  { return 1.0f/(1.0f + __expf(-x)); }
__device__ __forceinline__ float tanhf_(float x){ return 2.0f/(1.0f + __expf(-2.0f*x)) - 1.0f; }

__global__ void __launch_bounds__(256, 1)
lstm_persist(const float* __restrict__ x,   const float* __restrict__ Wih,
             const float* __restrict__ Whh, const float* __restrict__ bih,
             const float* __restrict__ bhh, const float* __restrict__ Whead,
             const float* __restrict__ bhead, float* __restrict__ out,
             char* __restrict__ ws)
{
    extern __shared__ char lds[];   // 128 KiB requested (forces 1 WG/CU); 16 KiB stage
    const int tid  = threadIdx.x;
    const int lane = tid & 63;
    const int wv   = tid >> 6;
    const int l15  = lane & 15, lq = lane >> 4, l7 = lane & 7;

    unsigned short* hb = (unsigned short*)(ws + HB_OFF);
    float* hT  = (float*)(ws + HT_OFF);
    int* flags = (int*)(ws + FLAGS_OFF);
    int* cnt   = (int*)(ws + CNT_OFF);

    // ---- self-organize by XCD: 32 WGs/XCD (capacity-guaranteed) -> 2 groups x 16 slices ----
    int* org = (int*)(lds + 131056);
    if (tid == 0) {
        unsigned xcd;
        asm volatile("s_getreg_b32 %0, hwreg(HW_REG_XCC_ID)" : "=s"(xcd));
        xcd &= 7u;
        int slot = __hip_atomic_fetch_add(&cnt[xcd], 1, __ATOMIC_RELAXED, __HIP_MEMORY_SCOPE_AGENT) & 31;
        org[0] = (int)xcd * 2 + (slot >> 4);
        org[1] = slot & 15;
    }
    __syncthreads();
    const int g  = org[0];
    const int sl = org[1];
    const int hbase = sl*32 + wv*8;        // wave's hidden-col base
    const int gsel  = l15 >> 3;            // gate select within N-tile

    // ---- W_hh fragments resident in VGPRs: 16 Ktiles x 2 Ntiles x 4 VGPR = 128 ----
    // Ntile0 cols = [gate i: hid 0..7 | gate f: hid 0..7]; Ntile1 = [g | o]
    short8 whh[KTH][2];
    #pragma unroll
    for (int kt = 0; kt < KTH; ++kt)
        #pragma unroll
        for (int nt = 0; nt < 2; ++nt) {
            int grow = (nt*2 + gsel)*HID + hbase + l7;
            const float4* p = (const float4*)(Whh + (size_t)grow*HID + kt*32 + lq*8);
            whh[kt][nt] = pack8(p[0], p[1]);
        }
    short8 wihf[2][2];
    #pragma unroll
    for (int kt = 0; kt < 2; ++kt)
        #pragma unroll
        for (int nt = 0; nt < 2; ++nt) {
            int grow = (nt*2 + gsel)*HID + hbase + l7;
            const float4* p = (const float4*)(Wih + (size_t)grow*INP + kt*32 + lq*8);
            wihf[kt][nt] = pack8(p[0], p[1]);
        }
    float bias0, bias1;
    { int gr = (0*2 + gsel)*HID + hbase + l7; bias0 = bih[gr] + bhh[gr]; }
    { int gr = (1*2 + gsel)*HID + hbase + l7; bias1 = bih[gr] + bhh[gr]; }

    unsigned short* hgrp = hb + (size_t)g*GROWS*HID;   // + slot*(BATCH*HID)
    float*          hTg  = hT + (size_t)g*GROWS*HID;
    int* flg = flags + g*TSTEPS;

    // staging map (R3's measured-conflict-free one): cluster skt stages (row sr, col-block skt)
    const int skt = tid >> 4, sr = tid & 15;
    char* swp = lds + skt*1024 + sr*16;            // + s*256 for k-sub-block s=0..3
    const char* srp = lds + lane*16;               // frag read: + kt*1024

    const float* xrow = x + ((size_t)(g*GROWS + l15)*TSTEPS)*INP + lq*8;

    f32x2 cst = {0.f, 0.f};
    const bool lo = (l15 < 8);

    // x prefetch for t=0
    float4 xv0 = *(const float4*)(xrow);
    float4 xv1 = *(const float4*)(xrow + 4);
    float4 xv2 = *(const float4*)(xrow + 32);
    float4 xv3 = *(const float4*)(xrow + 36);

    #pragma clang loop unroll(disable)
    for (int t = 0; t < TSTEPS; ++t) {
        // 4 independent accumulator chains: x kt0 -> a*, x kt1 -> b*
        f32x4 a0 = {bias0, bias0, bias0, bias0};
        f32x4 a1 = {bias1, bias1, bias1, bias1};
        f32x4 b0 = {0.f, 0.f, 0.f, 0.f};
        f32x4 b1 = {0.f, 0.f, 0.f, 0.f};
        {
            short8 af0 = pack8(xv0, xv1);
            short8 af1 = pack8(xv2, xv3);
            a0 = __builtin_amdgcn_mfma_f32_16x16x32_bf16(af0, wihf[0][0], a0, 0, 0, 0);
            a1 = __builtin_amdgcn_mfma_f32_16x16x32_bf16(af0, wihf[0][1], a1, 0, 0, 0);
            b0 = __builtin_amdgcn_mfma_f32_16x16x32_bf16(af1, wihf[1][0], b0, 0, 0, 0);
            b1 = __builtin_amdgcn_mfma_f32_16x16x32_bf16(af1, wihf[1][1], b1, 0, 0, 0);
        }
        __builtin_amdgcn_sched_barrier(0);

        // single-lane poll per wave: exec-mask reconvergence stalls the whole wave;
        // only 1 atomic txn per round per wave (was 64) -> no L2 atomic-pipe self-congestion
        if (t) {
            if (lane == 0) {
                const int* fl = flg + (t-1);
                while (__hip_atomic_load(fl, __ATOMIC_RELAXED, __HIP_MEMORY_SCOPE_AGENT) < NSL) {}
            }
            __builtin_amdgcn_sched_barrier(0);
            asm volatile("" ::: "memory");   // no hoisting stage loads above the poll
        }

        // stage h_{t-1} (slot t&7) into LDS, A-fragment order, via PLAIN cached loads:
        // ring-8 => stale-L1 lines structurally evicted; producer self-stores are its own h.
        {
            const char* gsrc = (const char*)(hgrp + (size_t)(t & (RING-1))*BATCH*HID)
                               + sr*1024 + skt*64;
            ull2 w0 = *(const ull2*)(gsrc);
            ull2 w1 = *(const ull2*)(gsrc + 16);
            ull2 w2 = *(const ull2*)(gsrc + 32);
            ull2 w3 = *(const ull2*)(gsrc + 48);
            *(ull2*)(swp      ) = w0;
            *(ull2*)(swp + 256) = w1;
            *(ull2*)(swp + 512) = w2;
            *(ull2*)(swp + 768) = w3;
        }
        __syncthreads();

        // x loads for t+1 AFTER the barrier: drained at end-of-step barrier (~800cy later),
        // fully hidden under h-MFMA + epilogue; never on the poll->MFMA critical path.
        if (t + 1 < TSTEPS) {
            const float* xn = xrow + (size_t)(t+1)*INP;
            xv0 = *(const float4*)(xn);      xv1 = *(const float4*)(xn + 4);
            xv2 = *(const float4*)(xn + 32); xv3 = *(const float4*)(xn + 36);
        }

        // h-part MFMAs: even kt -> a-chains, odd kt -> b-chains (halved dep depth)
        #pragma unroll
        for (int k2 = 0; k2 < 8; ++k2) {
            short8 ae = *(const short8*)(srp + (2*k2  )*1024);
            short8 ao = *(const short8*)(srp + (2*k2+1)*1024);
            a0 = __builtin_amdgcn_mfma_f32_16x16x32_bf16(ae, whh[2*k2  ][0], a0, 0, 0, 0);
            a1 = __builtin_amdgcn_mfma_f32_16x16x32_bf16(ae, whh[2*k2  ][1], a1, 0, 0, 0);
            b0 = __builtin_amdgcn_mfma_f32_16x16x32_bf16(ao, whh[2*k2+1][0], b0, 0, 0, 0);
            b1 = __builtin_amdgcn_mfma_f32_16x16x32_bf16(ao, whh[2*k2+1][1], b1, 0, 0, 0);
        }
        f32x4 acc0 = a0 + b0;
        f32x4 acc1 = a1 + b1;

        // lane-split epilogue: lo lanes rows {0,1}, hi lanes rows {2,3}
        // C layout col=lane&15, row=(lane>>4)*4+r; cols 0..7 = gates i/g, 8..15 = f/o
        float s0[4], s1[4];
        #pragma unroll
        for (int r = 0; r < 4; ++r) {
            s0[r] = __shfl_xor(acc0[r], 8);
            s1[r] = __shfl_xor(acc1[r], 8);
        }
        unsigned short* hbw = hgrp + (size_t)((t+1) & (RING-1))*BATCH*HID;
        #pragma unroll
        for (int rr = 0; rr < 2; ++rr) {
            float iv = lo ? acc0[rr] : s0[rr+2];
            float fv = lo ? s0[rr]   : acc0[rr+2];
            float gv = lo ? acc1[rr] : s1[rr+2];
            float ov = lo ? s1[rr]   : acc1[rr+2];
            float c  = sigm(fv)*cst[rr] + sigm(iv)*tanhf_(gv);
            cst[rr] = c;
            float h  = sigm(ov)*tanhf_(c);
            int row  = lq*4 + rr + (lo ? 0 : 2);
            int idx  = row*HID + hbase + l7;
            hbw[idx] = (unsigned short)(cvtpk(h, h) & 0xffffu);
            if (t == TSTEPS-1) hTg[idx] = h;
        }
        __syncthreads();   // implicit vmcnt(0): h stores (and x prefetch) drained -> publish
        if (tid == 0)
            __hip_atomic_fetch_add(&flg[t], 1, __ATOMIC_RELAXED, __HIP_MEMORY_SCOPE_AGENT);
    }

    // ---- heads: slice-0 WG of each group ----
    if (sl == 0) {
        if (tid == 0) {
            const int* fl = flg + (TSTEPS-1);
            while (__hip_atomic_load(fl, __ATOMIC_RELAXED, __HIP_MEMORY_SCOPE_AGENT) < NSL) {}
        }
        asm volatile("" ::: "memory");
        __syncthreads();
        // stage hT tile (16x512 f32 = 32 KiB) into LDS; these addresses were never
        // read before by this WG -> no stale-L1 path, plain loads safe.
        {
            const float4* gp = (const float4*)((const char*)hTg + tid*128);
            float4* wp = (float4*)(lds + tid*128);
            #pragma unroll
            for (int j = 0; j < 8; ++j) wp[j] = gp[j];
        }
        __syncthreads();
        const float* hsm = (const float*)lds;
        for (int idx = tid; idx < 6*GROWS*3; idx += 256) {
            int k = idx / (GROWS*3), rem = idx % (GROWS*3);
            int row = rem / 3, o = rem % 3;
            const float* wp = Whead + ((size_t)k*3 + o)*HID;
            const float* hp = hsm + row*HID;
            float s = 0.f;
            for (int hh = 0; hh < HID; hh += 4) {
                float4 hv = *(const float4*)(hp + hh);
                float4 wv = *(const float4*)(wp + hh);
                s += hv.x*wv.x + hv.y*wv.y + hv.z*wv.z + hv.w*wv.w;
            }
            out[((size_t)k*BATCH + g*GROWS + row)*3 + o] = s + bhead[k*3 + o];
        }
    }
}

extern "C" void kernel_launch(void* const* d_in, const int* in_sizes, int n_in,
                              void* d_out, int out_size, void* d_ws, size_t ws_size,
                              hipStream_t stream) {
    (void)in_sizes; (void)n_in; (void)out_size; (void)ws_size;
    const float* x     = (const float*)d_in[0];
    const float* Wih   = (const float*)d_in[1];
    const float* Whh   = (const float*)d_in[2];
    const float* bih   = (const float*)d_in[3];
    const float* bhh   = (const float*)d_in[4];
    const float* Whead = (const float*)d_in[5];
    const float* bhead = (const float*)d_in[6];
    char* ws = (char*)d_ws;

    (void)hipFuncSetAttribute((const void*)lstm_persist,
                              hipFuncAttributeMaxDynamicSharedMemorySize, 131072);

    // per-launch reset: h_0 slot 0 = 0, flags = 0, xcd slot counters = 0
    (void)hipMemsetAsync(ws + HB_OFF, 0, BATCH*HID*2, stream);
    (void)hipMemsetAsync(ws + FLAGS_OFF, 0, ZERO2_SZ, stream);

    hipLaunchKernelGGL(lstm_persist, dim3(NWG), dim3(256), 131072, stream,
                       x, Wih, Whh, bih, bhh, Whead, bhead, (float*)d_out, ws);
}